// Round 1
// baseline (430.766 us; speedup 1.0000x reference)
//
#include <hip/hip_runtime.h>
#include <hip/hip_bf16.h>

// Problem constants
// B=256, T=256, D=384, HD=64
constexpr int Bn = 256;
constexpr int Tn = 256;
constexpr int Dn = 384;
constexpr int HDn = 64;
constexpr long long BT = (long long)Bn * Tn; // 65536

// ---------------------------------------------------------------------------
// Kernel 1: QKV projection.  C[BT,192] = x[BT,384] @ [Wq;Wk;Wv]^T, stored bf16.
// Tile: 32 rows x 192 cols per block, 256 threads, thread = 2x12 micro-tile.
// LDS: x tile 32x388 f32 (padded: 2*388 % 32 = 8 -> conflict-free a-reads),
//      W k-chunk 32x192 f32.  Total ~73 KB -> 2 blocks/CU.
// ---------------------------------------------------------------------------
__global__ __launch_bounds__(256, 2) void qkv_proj(
    const float* __restrict__ x,
    const float* __restrict__ Wq,
    const float* __restrict__ Wk,
    const float* __restrict__ Wv,
    __hip_bfloat16* __restrict__ Qw,
    __hip_bfloat16* __restrict__ Kw,
    __hip_bfloat16* __restrict__ Vw)
{
    __shared__ float xs[32 * 388];
    __shared__ float wc[32 * 192];

    const int tid = threadIdx.x;
    const int tr = tid >> 4;       // 0..15
    const int tc = tid & 15;       // 0..15
    const int r0 = tr * 2;         // rows r0, r0+1
    const int c0 = tc * 12;        // cols c0..c0+11  (c0*4 bytes is 16B aligned)

    // ---- stage x tile (32 x 384 f32, coalesced float4) ----
    const float* xb = x + (size_t)blockIdx.x * (32 * 384);
    const float4* xb4 = (const float4*)xb;
#pragma unroll
    for (int rep = 0; rep < 12; ++rep) {
        int i = tid + 256 * rep;       // 0..3071  (3072 float4 = 32*384 floats)
        int row = i / 96;              // 96 float4 per row
        int kq  = i - row * 96;
        float4 v = xb4[i];
        *(float4*)&xs[row * 388 + kq * 4] = v;
    }

    float acc[2][12];
#pragma unroll
    for (int i2 = 0; i2 < 2; ++i2)
#pragma unroll
        for (int j = 0; j < 12; ++j) acc[i2][j] = 0.f;

    for (int kc = 0; kc < 12; ++kc) {
        __syncthreads();   // previous chunk's reads done (also covers xs writes at kc=0)
        // ---- stage W chunk: wc[kk][c] = W[c][kc*32+kk], 32x192 ----
#pragma unroll
        for (int rep = 0; rep < 6; ++rep) {
            int i = tid + 256 * rep;   // 0..1535
            int c  = i >> 3;           // 0..191
            int k4 = (i & 7) << 2;     // 0,4,..,28
            const float* wp = (c < 64)  ? (Wq + c * 384)
                             : (c < 128) ? (Wk + (c - 64) * 384)
                                         : (Wv + (c - 128) * 384);
            float4 w = *(const float4*)(wp + kc * 32 + k4);
            wc[(k4 + 0) * 192 + c] = w.x;
            wc[(k4 + 1) * 192 + c] = w.y;
            wc[(k4 + 2) * 192 + c] = w.z;
            wc[(k4 + 3) * 192 + c] = w.w;
        }
        __syncthreads();

        const float* xr0 = &xs[r0 * 388 + kc * 32];
        const float* xr1 = xr0 + 388;
#pragma unroll 8
        for (int kk = 0; kk < 32; ++kk) {
            float a0 = xr0[kk];
            float a1 = xr1[kk];
            const float* bp = &wc[kk * 192 + c0];
#pragma unroll
            for (int j = 0; j < 12; ++j) {
                float bv = bp[j];
                acc[0][j] += a0 * bv;
                acc[1][j] += a1 * bv;
            }
        }
    }

    // ---- epilogue: repack through LDS for coalesced bf16 stores ----
    __syncthreads();
    __hip_bfloat16* ob = (__hip_bfloat16*)wc;   // 32*192*2 = 12 KB, fits in wc
#pragma unroll
    for (int i2 = 0; i2 < 2; ++i2)
#pragma unroll
        for (int j = 0; j < 12; ++j)
            ob[(r0 + i2) * 192 + c0 + j] = __float2bfloat16(acc[i2][j]);
    __syncthreads();

    if (tid < 192) {
        int h    = tid >> 6;        // 0..2 -> Q,K,V
        int u    = tid & 63;
        int rr   = u >> 1;          // 0..31 local row
        int half = u & 1;           // 0/1: which 32-col half
        const uint4* src =
            (const uint4*)((const unsigned short*)wc + rr * 192 + h * 64 + half * 32);
        __hip_bfloat16* base = (h == 0) ? Qw : (h == 1) ? Kw : Vw;
        uint4* dst = (uint4*)(base + ((size_t)blockIdx.x * 32 + rr) * 64 + half * 32);
#pragma unroll
        for (int j = 0; j < 4; ++j) dst[j] = src[j];
    }
}

// ---------------------------------------------------------------------------
// Kernel 2: causal attention, one block per batch (256 blocks = 1/CU).
// K,V staged fp32 in LDS (128 KB). Thread t = query row t.
// Chunked (8-key) branchless online softmax; LDS reads are wave-uniform
// broadcasts (conflict-free). All per-thread arrays statically indexed.
// ---------------------------------------------------------------------------
__global__ __launch_bounds__(256, 1) void attn_kernel(
    const __hip_bfloat16* __restrict__ Qw,
    const __hip_bfloat16* __restrict__ Kw,
    const __hip_bfloat16* __restrict__ Vw,
    float* __restrict__ out)
{
    __shared__ float Kl[256 * 64];
    __shared__ float Vl[256 * 64];

    const int t = threadIdx.x;
    const int b = blockIdx.x;

    // ---- stage K, V (bf16 -> f32) ----
    const uint4* kp4 = (const uint4*)(Kw + (size_t)b * (256 * 64));
    const uint4* vp4 = (const uint4*)(Vw + (size_t)b * (256 * 64));
#pragma unroll
    for (int rep = 0; rep < 8; ++rep) {
        int i = t + 256 * rep;          // 0..2047, each uint4 = 8 bf16
        uint4 rk = kp4[i];
        uint4 rv = vp4[i];
        float* kd = &Kl[i * 8];
        float* vd = &Vl[i * 8];
        kd[0] = __uint_as_float(rk.x << 16); kd[1] = __uint_as_float(rk.x & 0xffff0000u);
        kd[2] = __uint_as_float(rk.y << 16); kd[3] = __uint_as_float(rk.y & 0xffff0000u);
        kd[4] = __uint_as_float(rk.z << 16); kd[5] = __uint_as_float(rk.z & 0xffff0000u);
        kd[6] = __uint_as_float(rk.w << 16); kd[7] = __uint_as_float(rk.w & 0xffff0000u);
        vd[0] = __uint_as_float(rv.x << 16); vd[1] = __uint_as_float(rv.x & 0xffff0000u);
        vd[2] = __uint_as_float(rv.y << 16); vd[3] = __uint_as_float(rv.y & 0xffff0000u);
        vd[4] = __uint_as_float(rv.z << 16); vd[5] = __uint_as_float(rv.z & 0xffff0000u);
        vd[6] = __uint_as_float(rv.w << 16); vd[7] = __uint_as_float(rv.w & 0xffff0000u);
    }

    // ---- own q row into registers ----
    float q[64];
    const uint4* qp = (const uint4*)(Qw + ((size_t)b * 256 + t) * 64);
#pragma unroll
    for (int i = 0; i < 8; ++i) {
        uint4 r = qp[i];
        q[i * 8 + 0] = __uint_as_float(r.x << 16);
        q[i * 8 + 1] = __uint_as_float(r.x & 0xffff0000u);
        q[i * 8 + 2] = __uint_as_float(r.y << 16);
        q[i * 8 + 3] = __uint_as_float(r.y & 0xffff0000u);
        q[i * 8 + 4] = __uint_as_float(r.z << 16);
        q[i * 8 + 5] = __uint_as_float(r.z & 0xffff0000u);
        q[i * 8 + 6] = __uint_as_float(r.w << 16);
        q[i * 8 + 7] = __uint_as_float(r.w & 0xffff0000u);
    }
    __syncthreads();

    float o[64];
#pragma unroll
    for (int h = 0; h < 64; ++h) o[h] = 0.f;
    float m = -INFINITY;
    float l = 0.f;

    for (int k0 = 0; k0 <= t; k0 += 8) {
        float s[8];
#pragma unroll
        for (int j = 0; j < 8; ++j) {
            int k   = k0 + j;
            int kcl = (k < 255) ? k : 255;       // clamp: masked lanes read safely
            const float* kp = &Kl[kcl * 64];
            float a0 = 0.f, a1 = 0.f, a2 = 0.f, a3 = 0.f;
#pragma unroll
            for (int h = 0; h < 64; h += 4) {
                a0 += q[h + 0] * kp[h + 0];
                a1 += q[h + 1] * kp[h + 1];
                a2 += q[h + 2] * kp[h + 2];
                a3 += q[h + 3] * kp[h + 3];
            }
            float sv = (a0 + a1) + (a2 + a3);
            s[j] = (k <= t) ? sv * 0.125f : -INFINITY;
        }
        float mx = s[0];
#pragma unroll
        for (int j = 1; j < 8; ++j) mx = fmaxf(mx, s[j]);
        float mnew = fmaxf(m, mx);              // finite from first chunk on
        float corr = __expf(m - mnew);          // -inf -> 0 on first chunk
        m = mnew;
        l *= corr;
#pragma unroll
        for (int h = 0; h < 64; ++h) o[h] *= corr;
        float p[8];
#pragma unroll
        for (int j = 0; j < 8; ++j) {
            p[j] = __expf(s[j] - m);            // masked: exp(-inf)=0
            l += p[j];
        }
#pragma unroll
        for (int j = 0; j < 8; ++j) {
            int kcl = (k0 + j < 255) ? (k0 + j) : 255;
            const float* vp = &Vl[kcl * 64];
            float pj = p[j];
#pragma unroll
            for (int h = 0; h < 64; ++h) o[h] += pj * vp[h];
        }
    }

    float inv = 1.f / l;
    float* op = out + ((size_t)b * 256 + t) * 64;
#pragma unroll
    for (int h = 0; h < 64; h += 4) {
        float4 v;
        v.x = o[h + 0] * inv;
        v.y = o[h + 1] * inv;
        v.z = o[h + 2] * inv;
        v.w = o[h + 3] * inv;
        *(float4*)&op[h] = v;
    }
}

// ---------------------------------------------------------------------------
extern "C" void kernel_launch(void* const* d_in, const int* in_sizes, int n_in,
                              void* d_out, int out_size, void* d_ws, size_t ws_size,
                              hipStream_t stream)
{
    const float* x  = (const float*)d_in[0];
    const float* Wq = (const float*)d_in[1];
    const float* Wk = (const float*)d_in[2];
    const float* Wv = (const float*)d_in[3];
    float* out = (float*)d_out;

    // Workspace layout: Q | K | V, each BT*64 bf16 (8 MB) -> 24 MB total.
    __hip_bfloat16* Qw = (__hip_bfloat16*)d_ws;
    __hip_bfloat16* Kw = Qw + (size_t)BT * HDn;
    __hip_bfloat16* Vw = Kw + (size_t)BT * HDn;

    qkv_proj<<<dim3(2048), dim3(256), 0, stream>>>(x, Wq, Wk, Wv, Qw, Kw, Vw);
    attn_kernel<<<dim3(256), dim3(256), 0, stream>>>(Qw, Kw, Vw, out);
}

// Round 2
// 50.762 us; speedup vs baseline: 8.4860x; 8.4860x over previous
//
#include <hip/hip_runtime.h>

// B=256, T=256, D=384, HD=64
typedef __attribute__((ext_vector_type(8))) short bf16x8;
typedef __attribute__((ext_vector_type(4))) float f32x4;

__device__ inline unsigned short f2bf(float f) {
    unsigned u = __float_as_uint(f);
    return (unsigned short)((u + 0x7fffu + ((u >> 16) & 1u)) >> 16);
}

// ---------------------------------------------------------------------------
// Kernel 0: concatenate + convert W = [Wq;Wk;Wv] (192x384 f32) -> bf16
// ---------------------------------------------------------------------------
__global__ void wconv(const float* __restrict__ Wq, const float* __restrict__ Wk,
                      const float* __restrict__ Wv, short* __restrict__ Wcat) {
    int i = blockIdx.x * 256 + threadIdx.x;
    if (i >= 192 * 384) return;
    int row = i / 384;
    int col = i - row * 384;
    const float* src = row < 64 ? (Wq + row * 384)
                     : row < 128 ? (Wk + (row - 64) * 384)
                                 : (Wv + (row - 128) * 384);
    Wcat[i] = (short)f2bf(src[col]);
}

// ---------------------------------------------------------------------------
// Kernel 1: QKV projection via MFMA.  C[65536,192] = bf16(x) @ bf16(W)^T.
// Block: 128 rows x 192 cols, 256 threads (4 waves as 2Mx2N, wave = 64x96).
// LDS rows padded to 72 bf16 (144 B = 4 banks offset -> 2-way = free).
// Both A and B fragments use the identical k-gather -> layout-permutation-
// immune; only C/D layout (verified: col=l&15, row=4*(l>>4)+r) is relied on.
// ---------------------------------------------------------------------------
__global__ __launch_bounds__(256) void qkv_proj_mfma(
    const float* __restrict__ x, const short* __restrict__ Wcat,
    short* __restrict__ Qw, short* __restrict__ Kw, short* __restrict__ Vw) {
    __shared__ short xs[128 * 72];
    __shared__ short wsh[192 * 72];
    const int tid = threadIdx.x;
    const int wv = tid >> 6, lane = tid & 63;
    const int g = lane >> 4, c = lane & 15;
    const int wm = (wv >> 1) * 64, wn = (wv & 1) * 96;
    const long long m0 = (long long)blockIdx.x * 128;

    f32x4 acc[4][6];
#pragma unroll
    for (int i = 0; i < 4; ++i)
#pragma unroll
        for (int j = 0; j < 6; ++j) acc[i][j] = (f32x4){0.f, 0.f, 0.f, 0.f};

    for (int kc = 0; kc < 6; ++kc) {
        // stage x tile 128x64: f32 -> bf16, coalesced float4 reads
#pragma unroll
        for (int p = 0; p < 8; ++p) {
            int r = p * 16 + (tid >> 4);
            int c4 = tid & 15;
            float4 v = *(const float4*)(x + (m0 + r) * 384 + kc * 64 + c4 * 4);
            unsigned lo = (unsigned)f2bf(v.x) | ((unsigned)f2bf(v.y) << 16);
            unsigned hi = (unsigned)f2bf(v.z) | ((unsigned)f2bf(v.w) << 16);
            *(uint2*)&xs[r * 72 + c4 * 4] = make_uint2(lo, hi);
        }
        // stage W tile 192x64 bf16
#pragma unroll
        for (int p = 0; p < 12; ++p) {
            int idx = tid + 256 * p;
            int r = idx >> 4;
            int c2 = idx & 15;
            uint2 w2 = *(const uint2*)(Wcat + r * 384 + kc * 64 + c2 * 4);
            *(uint2*)&wsh[r * 72 + c2 * 4] = w2;
        }
        __syncthreads();
#pragma unroll
        for (int ks = 0; ks < 2; ++ks) {
            bf16x8 af[4], bfr[6];
#pragma unroll
            for (int mi = 0; mi < 4; ++mi)
                af[mi] = *(const bf16x8*)&xs[(wm + 16 * mi + c) * 72 + ks * 32 + g * 8];
#pragma unroll
            for (int nj = 0; nj < 6; ++nj)
                bfr[nj] = *(const bf16x8*)&wsh[(wn + 16 * nj + c) * 72 + ks * 32 + g * 8];
#pragma unroll
            for (int mi = 0; mi < 4; ++mi)
#pragma unroll
                for (int nj = 0; nj < 6; ++nj)
                    acc[mi][nj] = __builtin_amdgcn_mfma_f32_16x16x32_bf16(
                        af[mi], bfr[nj], acc[mi][nj], 0, 0, 0);
        }
        __syncthreads();
    }
    // epilogue: C/D layout row = 4g+r, col = c (within each 16x16 tile)
#pragma unroll
    for (int mi = 0; mi < 4; ++mi) {
#pragma unroll
        for (int nj = 0; nj < 6; ++nj) {
            int colb = wn + 16 * nj;                    // wave-uniform
            short* dst = colb < 64 ? Qw : (colb < 128 ? Kw : Vw);
            int hc = (colb & 63) + c;
#pragma unroll
            for (int r = 0; r < 4; ++r) {
                long long row = m0 + wm + 16 * mi + 4 * g + r;
                dst[row * 64 + hc] = (short)f2bf(acc[mi][nj][r]);
            }
        }
    }
}

// ---------------------------------------------------------------------------
// Kernel 2: causal attention via MFMA. Block = 1 batch, 8 waves (512 thr).
// Wave w handles q-tiles [16w, 16w+16) and [240-16w, 256-16w): exactly 9
// kv32-tiles each -> perfectly balanced. K in LDS padded [256][72]; V in LDS
// transposed [64][264] with XOR swizzle ((h>>3)&7)<<3 on the short index
// (makes both the 2B transpose writes and b128 frag reads conflict-free).
// P round-trips through a per-wave LDS buffer to fix C/D -> A-frag layout.
// ---------------------------------------------------------------------------
__global__ __launch_bounds__(512) void attn_mfma(
    const short* __restrict__ Qw, const short* __restrict__ Kw,
    const short* __restrict__ Vw, float* __restrict__ out) {
    __shared__ short Ksh[256 * 72];
    __shared__ short Vt[64 * 264];
    __shared__ short Pb[8][16 * 40];
    const int tid = threadIdx.x;
    const int wv = tid >> 6, lane = tid & 63;
    const int g = lane >> 4, c = lane & 15;
    const int b = blockIdx.x;
    const short* Qg = Qw + b * 16384;
    const short* Kg = Kw + b * 16384;
    const short* Vg = Vw + b * 16384;

    // stage K [k][h] padded
#pragma unroll
    for (int p = 0; p < 4; ++p) {
        int idx = tid + 512 * p;
        int r = idx >> 3, q8 = idx & 7;
        *(uint4*)&Ksh[r * 72 + q8 * 8] = *(const uint4*)(Kg + r * 64 + q8 * 8);
    }
    // stage V transposed + swizzled: element (k=r, h=8*q8+i)
#pragma unroll
    for (int p = 0; p < 4; ++p) {
        int idx = tid + 512 * p;
        int r = idx >> 3, q8 = idx & 7;
        uint4 v = *(const uint4*)(Vg + r * 64 + q8 * 8);
        unsigned vw[4] = {v.x, v.y, v.z, v.w};
        int swz = (q8 & 7) << 3;
#pragma unroll
        for (int w2 = 0; w2 < 4; ++w2) {
            int h0 = q8 * 8 + w2 * 2;
            Vt[((h0 + 0) * 264 + r) ^ swz] = (short)(vw[w2] & 0xffff);
            Vt[((h0 + 1) * 264 + r) ^ swz] = (short)(vw[w2] >> 16);
        }
    }
    __syncthreads();

    for (int half = 0; half < 2; ++half) {
        const int q0 = (half == 0) ? 16 * wv : 240 - 16 * wv;
        bf16x8 qf0 = *(const bf16x8*)(Qg + (q0 + c) * 64 + g * 8);
        bf16x8 qf1 = *(const bf16x8*)(Qg + (q0 + c) * 64 + 32 + g * 8);
        f32x4 o[4];
#pragma unroll
        for (int nj = 0; nj < 4; ++nj) o[nj] = (f32x4){0.f, 0.f, 0.f, 0.f};
        float m[4] = {-INFINITY, -INFINITY, -INFINITY, -INFINITY};
        float ls[4] = {0.f, 0.f, 0.f, 0.f};
        const int jmax = (q0 + 15) >> 5;

        for (int j = 0; j <= jmax; ++j) {
            f32x4 s0 = {0.f, 0.f, 0.f, 0.f}, s1 = {0.f, 0.f, 0.f, 0.f};
            {
                bf16x8 kf;
                kf = *(const bf16x8*)&Ksh[(32 * j + c) * 72 + g * 8];
                s0 = __builtin_amdgcn_mfma_f32_16x16x32_bf16(qf0, kf, s0, 0, 0, 0);
                kf = *(const bf16x8*)&Ksh[(32 * j + c) * 72 + 32 + g * 8];
                s0 = __builtin_amdgcn_mfma_f32_16x16x32_bf16(qf1, kf, s0, 0, 0, 0);
                kf = *(const bf16x8*)&Ksh[(32 * j + 16 + c) * 72 + g * 8];
                s1 = __builtin_amdgcn_mfma_f32_16x16x32_bf16(qf0, kf, s1, 0, 0, 0);
                kf = *(const bf16x8*)&Ksh[(32 * j + 16 + c) * 72 + 32 + g * 8];
                s1 = __builtin_amdgcn_mfma_f32_16x16x32_bf16(qf1, kf, s1, 0, 0, 0);
            }
            float t0[4], t1[4];
#pragma unroll
            for (int r = 0; r < 4; ++r) {
                t0[r] = s0[r] * 0.125f;
                t1[r] = s1[r] * 0.125f;
            }
            if (j == jmax) {   // wave-uniform branch: diagonal tile, apply mask
                int q = q0 + 4 * g;
#pragma unroll
                for (int r = 0; r < 4; ++r) {
                    if (32 * j + c > q + r) t0[r] = -INFINITY;
                    if (32 * j + 16 + c > q + r) t1[r] = -INFINITY;
                }
            }
            float corr[4], p0[4], p1[4];
#pragma unroll
            for (int r = 0; r < 4; ++r) {
                float v = fmaxf(t0[r], t1[r]);
#pragma unroll
                for (int off = 1; off < 16; off <<= 1) v = fmaxf(v, __shfl_xor(v, off, 16));
                float mn = fmaxf(m[r], v);
                corr[r] = __expf(m[r] - mn);   // first tile: exp(-inf)=0
                m[r] = mn;
                p0[r] = __expf(t0[r] - mn);
                p1[r] = __expf(t1[r] - mn);
                float rs = p0[r] + p1[r];
#pragma unroll
                for (int off = 1; off < 16; off <<= 1) rs += __shfl_xor(rs, off, 16);
                ls[r] = ls[r] * corr[r] + rs;
            }
#pragma unroll
            for (int nj = 0; nj < 4; ++nj) {
                f32x4 t = o[nj];
                t[0] *= corr[0]; t[1] *= corr[1]; t[2] *= corr[2]; t[3] *= corr[3];
                o[nj] = t;
            }
            // P -> LDS (C/D layout rows) -> A-frag read (same-wave RAW, in-order LDS)
            short* pb = Pb[wv];
#pragma unroll
            for (int r = 0; r < 4; ++r) {
                pb[(4 * g + r) * 40 + c]      = (short)f2bf(p0[r]);
                pb[(4 * g + r) * 40 + 16 + c] = (short)f2bf(p1[r]);
            }
            bf16x8 pa = *(const bf16x8*)&pb[c * 40 + g * 8];
#pragma unroll
            for (int nj = 0; nj < 4; ++nj) {
                int h = 16 * nj + c;
                int swz = ((2 * nj + (c >> 3)) & 7) << 3;
                bf16x8 vf = *(const bf16x8*)&Vt[(h * 264 + 32 * j + g * 8) ^ swz];
                o[nj] = __builtin_amdgcn_mfma_f32_16x16x32_bf16(pa, vf, o[nj], 0, 0, 0);
            }
        }
        float inv[4];
#pragma unroll
        for (int r = 0; r < 4; ++r) inv[r] = 1.f / ls[r];
        float* ob = out + ((size_t)b * 256 + q0) * 64;
#pragma unroll
        for (int nj = 0; nj < 4; ++nj)
#pragma unroll
            for (int r = 0; r < 4; ++r)
                ob[(4 * g + r) * 64 + 16 * nj + c] = o[nj][r] * inv[r];
    }
}

// ---------------------------------------------------------------------------
extern "C" void kernel_launch(void* const* d_in, const int* in_sizes, int n_in,
                              void* d_out, int out_size, void* d_ws, size_t ws_size,
                              hipStream_t stream) {
    const float* x  = (const float*)d_in[0];
    const float* Wq = (const float*)d_in[1];
    const float* Wk = (const float*)d_in[2];
    const float* Wv = (const float*)d_in[3];
    float* out = (float*)d_out;

    // ws: Q | K | V (each 65536*64 bf16 = 8 MB) | Wcat (192*384 bf16)
    short* Qws  = (short*)d_ws;
    short* Kws  = Qws + (size_t)65536 * 64;
    short* Vws  = Kws + (size_t)65536 * 64;
    short* Wcat = Vws + (size_t)65536 * 64;

    wconv<<<dim3(288), dim3(256), 0, stream>>>(Wq, Wk, Wv, Wcat);
    qkv_proj_mfma<<<dim3(512), dim3(256), 0, stream>>>(x, Wcat, Qws, Kws, Vws);
    attn_mfma<<<dim3(256), dim3(512), 0, stream>>>(Qws, Kws, Vws, out);
}